// Round 1
// baseline (236.715 us; speedup 1.0000x reference)
//
#include <hip/hip_runtime.h>

#define Bdim 512
#define Tdim 2000
#define Ddim 20
#define Hdim 128
#define Cdim 10
#define TB 128          // timesteps per LDS tile
#define BETA 0.95f
#define THR 0.8f

__global__ __launch_bounds__(Hdim, 1) void snn_fused_kernel(
    const float* __restrict__ x,   // [B,T,D]
    const float* __restrict__ W1,  // [H,D]
    const float* __restrict__ b1,  // [H]
    const float* __restrict__ W2,  // [C,H]
    const float* __restrict__ b2,  // [C]
    float* __restrict__ out)       // [B,C]
{
    const int b = blockIdx.x;
    const int h = threadIdx.x;

    __shared__ float xs[2][TB * Ddim];   // 2 * 10240 B
    __shared__ float cnt_s[Hdim];

    // W1 row + bias in registers
    float w[Ddim];
#pragma unroll
    for (int d = 0; d < Ddim; ++d) w[d] = W1[h * Ddim + d];
    const float bias = b1[h];

    const float* xb = x + (size_t)b * Tdim * Ddim;

    // stage tile 0
    {
        const int n4 = TB * Ddim / 4;   // 640
        const float4* src = reinterpret_cast<const float4*>(xb);
        float4* dst = reinterpret_cast<float4*>(xs[0]);
        if (h         < n4) dst[h]         = src[h];
        if (h + 128   < n4) dst[h + 128]   = src[h + 128];
        if (h + 256   < n4) dst[h + 256]   = src[h + 256];
        if (h + 384   < n4) dst[h + 384]   = src[h + 384];
        if (h + 512   < n4) dst[h + 512]   = src[h + 512];
    }
    __syncthreads();

    float mem = 0.0f;
    float cnt = 0.0f;
    int cur = 0;
    const int NT = (Tdim + TB - 1) / TB;   // 16

    for (int tile = 0; tile < NT; ++tile) {
        const int t0 = tile * TB;
        const int nt = min(TB, Tdim - t0);

        // prefetch next tile into registers (guards match stores below)
        float4 r0, r1, r2, r3, r4;
        int n4n = 0;
        if (tile + 1 < NT) {
            const int t1 = (tile + 1) * TB;
            n4n = (min(TB, Tdim - t1) * Ddim) / 4;
            const float4* src = reinterpret_cast<const float4*>(xb + (size_t)t1 * Ddim);
            if (h         < n4n) r0 = src[h];
            if (h + 128   < n4n) r1 = src[h + 128];
            if (h + 256   < n4n) r2 = src[h + 256];
            if (h + 384   < n4n) r3 = src[h + 384];
            if (h + 512   < n4n) r4 = src[h + 512];
        }

        // compute current tile
        const float* xt = xs[cur];
#pragma unroll 4
        for (int tl = 0; tl < nt; ++tl) {
            const float* xp = xt + tl * Ddim;
            const float4 a0 = *reinterpret_cast<const float4*>(xp);
            const float4 a1 = *reinterpret_cast<const float4*>(xp + 4);
            const float4 a2 = *reinterpret_cast<const float4*>(xp + 8);
            const float4 a3 = *reinterpret_cast<const float4*>(xp + 12);
            const float4 a4 = *reinterpret_cast<const float4*>(xp + 16);
            // 4 independent FMA chains of depth 5
            float s0 = fmaf(a0.x, w[0], fmaf(a1.x, w[4], fmaf(a2.x, w[8],  fmaf(a3.x, w[12], a4.x * w[16]))));
            float s1 = fmaf(a0.y, w[1], fmaf(a1.y, w[5], fmaf(a2.y, w[9],  fmaf(a3.y, w[13], a4.y * w[17]))));
            float s2 = fmaf(a0.z, w[2], fmaf(a1.z, w[6], fmaf(a2.z, w[10], fmaf(a3.z, w[14], a4.z * w[18]))));
            float s3 = fmaf(a0.w, w[3], fmaf(a1.w, w[7], fmaf(a2.w, w[11], fmaf(a3.w, w[15], a4.w * w[19]))));
            const float curr = ((s0 + s1) + (s2 + s3)) + bias;
            // snntorch Leaky, subtract-reset based on PREVIOUS mem
            const float reset = (mem > THR) ? THR : 0.0f;
            mem = fmaf(BETA, mem, curr) - reset;
            cnt += (mem > THR) ? 1.0f : 0.0f;
        }

        // store prefetched tile into the other buffer, then sync
        if (tile + 1 < NT) {
            float4* dst = reinterpret_cast<float4*>(xs[cur ^ 1]);
            if (h         < n4n) dst[h]         = r0;
            if (h + 128   < n4n) dst[h + 128]   = r1;
            if (h + 256   < n4n) dst[h + 256]   = r2;
            if (h + 384   < n4n) dst[h + 384]   = r3;
            if (h + 512   < n4n) dst[h + 512]   = r4;
            __syncthreads();
            cur ^= 1;
        }
    }

    // fused epilogue: logits[b,:] from spike counts of this block
    cnt_s[h] = cnt;
    __syncthreads();
    if (h < Cdim) {
        float dot = 0.0f;
#pragma unroll
        for (int k = 0; k < Hdim; ++k)
            dot = fmaf(cnt_s[k], W2[h * Hdim + k], dot);
        const float Tf = (float)Tdim;
        const float scale = 1.0f / Tf + 0.1f / (Tf + 1e-6f);
        out[b * Cdim + h] = fmaf(dot, scale, 1.1f * b2[h]);
    }
}

extern "C" void kernel_launch(void* const* d_in, const int* in_sizes, int n_in,
                              void* d_out, int out_size, void* d_ws, size_t ws_size,
                              hipStream_t stream) {
    const float* x  = (const float*)d_in[0];
    const float* W1 = (const float*)d_in[1];
    const float* b1 = (const float*)d_in[2];
    const float* W2 = (const float*)d_in[3];
    const float* b2 = (const float*)d_in[4];
    float* out = (float*)d_out;

    snn_fused_kernel<<<dim3(Bdim), dim3(Hdim), 0, stream>>>(x, W1, b1, W2, b2, out);
}